// Round 13
// baseline (104527.380 us; speedup 1.0000x reference)
//
#include <hip/hip_runtime.h>
#include <hip/hip_bf16.h>
#include <math.h>
#include <stdio.h>

#define NWG 256
#define NT  512
#define T_  128
#define L_  8
typedef unsigned short ushort_t;
typedef unsigned long long u64;

struct P {
  const float *data,*r,*y_d,*wte_w,*wte_b,*wpe,*ln1_w,*ln1_b,*qkv_w,*qkv_b,
              *proj_w,*proj_b,*ln2_w,*ln2_b,*fc_w,*fc_b,*mproj_w,*mproj_b,
              *lnf_w,*lnf_b,*head_w,*head_b;
  float *out, *y, *u, *h0, *h1;
  ushort_t *qT, *oT, *gT;                 // bf16 activations
  ushort_t *wq, *wp, *wf, *wm;            // bf16 weights (converted at launch)
  ushort_t *Kc, *Vc;
  u64 *sync;
};

__device__ __forceinline__ float bf2f(ushort_t u) {
  return __uint_as_float(((unsigned)u) << 16);
}
__device__ __forceinline__ ushort_t f2bf(float f) {
  __hip_bfloat16 b = __float2bfloat16(f);
  return *reinterpret_cast<ushort_t*>(&b);
}

// fp32 -> bf16 weight conversion (idempotent; replayed per graph launch).
__global__ void wconv(const float* __restrict__ src, ushort_t* __restrict__ dst, int n) {
  int i = blockIdx.x * blockDim.x + threadIdx.x;
  const int stride = gridDim.x * blockDim.x;
  for (; i < n; i += stride) dst[i] = f2bf(src[i]);
}

// ---- Barrier v4: flag-publish, split arrive/wait. ----
// Layout: gs[0]=gen; gs[8..15]=done[8] (one 64B line); gs[16+x*16]=leaf[x].
// arrive: leaf RMW relaxed; leaf-last (one per XCD) RELEASE-stores done[x]=bt
// (ONE wbL2 per XCD, flushing all 32 WGs' data — their stores are already in
// L2 via __syncthreads vmcnt(0)). All 8 leaf-lasts poll the done line and
// idempotently publish gen via fetch_max RELEASE (monotonic, no regression).
// Acquire FENCES give transitivity (fence after relaxed reads that observed
// the releases). No root RMW chain; waiters overlap the wait with prefetch.
__device__ __forceinline__ void g_arrive(u64* gs, int xcd, u64 bt) {
  __syncthreads();
  if (threadIdx.x == 0) {
    const u64 lo = __hip_atomic_fetch_add(gs + 16 + xcd * 16, 1ULL,
                                          __ATOMIC_RELAXED, __HIP_MEMORY_SCOPE_AGENT);
    if (lo == 31ULL) {
      __hip_atomic_store(gs + 16 + xcd * 16, 0ULL, __ATOMIC_RELAXED, __HIP_MEMORY_SCOPE_AGENT);
      __hip_atomic_store(gs + 8 + xcd, bt, __ATOMIC_RELEASE, __HIP_MEMORY_SCOPE_AGENT);
      for (;;) {
        bool all = true;
        #pragma unroll
        for (int x = 0; x < 8; ++x)
          all &= (__hip_atomic_load(gs + 8 + x, __ATOMIC_RELAXED, __HIP_MEMORY_SCOPE_AGENT) >= bt);
        if (all) break;
        __builtin_amdgcn_s_sleep(1);
      }
      __builtin_amdgcn_fence(__ATOMIC_ACQUIRE, "agent");
      (void)__hip_atomic_fetch_max(gs, bt, __ATOMIC_RELEASE, __HIP_MEMORY_SCOPE_AGENT);
    }
  }
  // no trailing syncthreads: waves proceed to barrier-independent prefetch.
}

__device__ __forceinline__ void g_wait(u64* gs, u64 bt) {
  if (threadIdx.x == 0) {
    while (__hip_atomic_load(gs, __ATOMIC_RELAXED, __HIP_MEMORY_SCOPE_AGENT) < bt)
      __builtin_amdgcn_s_sleep(1);
    __builtin_amdgcn_fence(__ATOMIC_ACQUIRE, "agent");
  }
  __syncthreads();
}

// Bank-swizzle for slab[k][16] (r9-proven): word k*16 + (m ^ (((k>>1)&3)<<2)).
__device__ __forceinline__ int swz4(int k) { return ((k >> 1) & 3); }

// Stage slab[512][16] (swizzled) from bf16 row-major src rows of width W.
__device__ __forceinline__ void stage_bf(const ushort_t* __restrict__ src, int W,
                                         int row0, int k0, float* slab) {
  const int tid = threadIdx.x;
  const int m = tid >> 5, q = tid & 31;
  const ushort_t* sp = src + (size_t)(row0 + m) * W + k0;
  #pragma unroll
  for (int i = 0; i < 16; ++i) {
    const int k = q + i * 32;
    slab[k * 16 + (m ^ (swz4(k) << 2))] = bf2f(sp[k]);
  }
}

// Read 16 fp32 rows of h, per-row LN stats via 32-lane shfl, write
// normalized values into slab (swizzled).
__device__ __forceinline__ void stats_ln(const float* __restrict__ h,
                                         const float* __restrict__ lnw,
                                         const float* __restrict__ lnb,
                                         int rb, float* slab) {
  const int tid = threadIdx.x;
  const int m = tid >> 5, q = tid & 31;
  const float* hp = h + (size_t)(rb * 16 + m) * 512;
  float vv[16];
  float s = 0.f, s2 = 0.f;
  #pragma unroll
  for (int i = 0; i < 16; ++i) {
    const int k = q + i * 32;
    const float v = hp[k];
    vv[i] = v; s += v; s2 += v * v;
  }
  #pragma unroll
  for (int mk = 1; mk <= 16; mk <<= 1) { s += __shfl_xor(s, mk); s2 += __shfl_xor(s2, mk); }
  const float mu = s * (1.f / 512.f);
  const float rs = rsqrtf(s2 * (1.f / 512.f) - mu * mu + 1e-5f);
  #pragma unroll
  for (int i = 0; i < 16; ++i) {
    const int k = q + i * 32;
    slab[k * 16 + (m ^ (swz4(k) << 2))] = (vv[i] - mu) * rs * lnw[k] + lnb[k];
  }
}

#define FMA_ALL(W_, A_) \
  A_[0]+=W_*a0.x; A_[1]+=W_*a0.y; A_[2]+=W_*a0.z; A_[3]+=W_*a0.w; \
  A_[4]+=W_*a1.x; A_[5]+=W_*a1.y; A_[6]+=W_*a1.z; A_[7]+=W_*a1.w; \
  A_[8]+=W_*a2.x; A_[9]+=W_*a2.y; A_[10]+=W_*a2.z; A_[11]+=W_*a2.w; \
  A_[12]+=W_*a3.x; A_[13]+=W_*a3.y; A_[14]+=W_*a3.z; A_[15]+=W_*a3.w;

// Prefetch the WG's 16 weight dwords for one 512-k chunk (registers only).
template<int N>
__device__ __forceinline__ void w_pref(const ushort_t* __restrict__ Wbase, unsigned* w) {
  const int tid = threadIdx.x;
  const int wv = tid >> 6, lane = tid & 63;
  const int kq = lane >> 4, cp = lane & 15;
  const int r0 = wv * 64 + kq;
  const ushort_t* Wg = Wbase + (size_t)r0 * N + cp * 2;
  #pragma unroll
  for (int u = 0; u < 16; ++u)
    w[u] = *(const unsigned*)(Wg + (size_t)(u * 4) * N);
}

// FMA half of the chunk GEMM using prefetched weights.
__device__ __forceinline__ void gemm_fma(const float* __restrict__ slab,
                                         const unsigned* w, float* acc0, float* acc1) {
  const int tid = threadIdx.x;
  const int wv = tid >> 6, lane = tid & 63;
  const int kq = lane >> 4;
  const int r0 = wv * 64 + kq;
  #pragma unroll
  for (int u = 0; u < 16; ++u) {
    const int row = r0 + u * 4;
    const float4* b4 = (const float4*)(slab + row * 16);
    const int c4 = swz4(row);
    const float4 a0 = b4[0 ^ c4], a1 = b4[1 ^ c4], a2 = b4[2 ^ c4], a3 = b4[3 ^ c4];
    const float wx = bf2f((ushort_t)w[u]), wy = bf2f((ushort_t)(w[u] >> 16));
    FMA_ALL(wx, acc0)
    FMA_ALL(wy, acc1)
  }
}

template<int N>
__device__ __forceinline__ void gemm_acc(const ushort_t* __restrict__ Wbase,
                                         const float* __restrict__ slab,
                                         float* acc0, float* acc1) {
  unsigned w[16];
  w_pref<N>(Wbase, w);
  gemm_fma(slab, w, acc0, acc1);
}

// Cross-lane (kq) + cross-wave reduction; returns value for (col=tid&31, m=tid>>5).
__device__ __forceinline__ float gemm_finish(float* acc0, float* acc1, float* redw) {
  const int tid = threadIdx.x;
  const int wv = tid >> 6, lane = tid & 63;
  #pragma unroll
  for (int m = 0; m < 16; ++m) {
    acc0[m] += __shfl_xor(acc0[m], 16); acc1[m] += __shfl_xor(acc1[m], 16);
    acc0[m] += __shfl_xor(acc0[m], 32); acc1[m] += __shfl_xor(acc1[m], 32);
  }
  if (lane < 16) {
    float* rp = redw + wv * 528 + lane * 33;
    #pragma unroll
    for (int m = 0; m < 16; ++m) { rp[m] = acc0[m]; rp[16 + m] = acc1[m]; }
  }
  __syncthreads();
  const int col = tid & 31, m2 = tid >> 5;
  float s = 0.f;
  #pragma unroll
  for (int w2 = 0; w2 < 8; ++w2)
    s += redw[w2 * 528 + (col >> 1) * 33 + (col & 1) * 16 + m2];
  return s;
}

#define ACC_INIT float acc0[16], acc1[16]; \
  _Pragma("unroll") for (int m_ = 0; m_ < 16; ++m_) { acc0[m_] = 0.f; acc1[m_] = 0.f; }

__global__ __launch_bounds__(NT, 1) void gptloop(P p) {
  const int bid = blockIdx.x, tid = threadIdx.x;
  const int xcd = bid & 7, slot = bid >> 3;   // bid%8 = XCD (m09); slot 0..31
  u64* gs = p.sync;
  u64 bt = 1;

  __shared__ float slab[8192];
  __shared__ float redw[8 * 528];
  __shared__ float red1[512], red2[512];
  __shared__ float att_s[2][128];
  __shared__ float qv_s[2][64];
  __shared__ float inv_s[2];
  __shared__ float bc[4];

  unsigned wA[16], wC[16], wD[16], wE[16];
  const int cbA = xcd * 6 + (slot >> 2);      // stage A col-block (slot<24)
  const int cbC = xcd * 2 + (slot >> 2);      // stage C/E col-block (slot<8)
  const int cbD = xcd * 8 + (slot >> 2);      // stage D col-block

  // ---- init: y/u + embed(st=0) -> h0 (64 WGs, one row each, XCD-spread) ----
  if (slot < 8) {
    const int b = xcd * 8 + slot, t = tid;
    const float y0 = p.y_d[b * 256], y1 = p.y_d[b * 256 + 1];
    const float e0 = p.r[b * 256] - y0, e1 = p.r[b * 256 + 1] - y1;
    p.h0[b * 512 + t] = e0 * p.wte_w[t] + e1 * p.wte_w[512 + t]
                      + 191.713f * p.wte_w[1024 + t] + 215.888f * p.wte_w[1536 + t]
                      + p.wte_b[t] + p.wpe[t];
    if (t < 2) {
      p.y[b * 2 + t] = t ? y1 : y0;
      p.u[b * 2 + t] = t ? 215.888f : 191.713f;
    }
  }
  g_arrive(gs, xcd, bt);
  if (slot < 24) w_pref<1536>(p.wq + cbA * 32, wA);
  g_wait(gs, bt); ++bt;

  for (int st = 0; st < T_; ++st) {
    for (int l = 0; l < L_; ++l) {
      // ==== A: LN1-stats + qkv full-K (192 WGs: xcd owns 6 cb x 4 rb) ====
      if (slot < 24) {
        const int rb = slot & 3;
        stats_ln(p.h0, p.ln1_w + l * 512, p.ln1_b + l * 512, rb, slab);
        __syncthreads();
        ACC_INIT
        gemm_fma(slab, wA, acc0, acc1);
        float v = gemm_finish(acc0, acc1, redw);
        const int col = tid & 31, m = tid >> 5;
        const int gcol = cbA * 32 + col;
        v += p.qkv_b[l * 1536 + gcol];
        const int part = gcol >> 9, head = (gcol & 511) >> 6, off = gcol & 63;
        const int b = rb * 16 + m;
        if (part == 0) {
          p.qT[b * 512 + gcol] = f2bf(v * 0.125f);   // fold 1/sqrt(HD)
        } else {
          ushort_t* dst = (part == 1) ? p.Kc : p.Vc;
          dst[((size_t)(l * 64 + b) * 8 + head) * 8192 + st * 64 + off] = f2bf(v);
        }
      }
      g_arrive(gs, xcd, bt);
      g_wait(gs, bt); ++bt;

      // ==== B: attention (256 WGs x 2 (b,h) pairs) -> oT ====
      {
        const int pp = tid >> 8, t = tid & 255;
        const int pid = bid * 2 + pp, b = pid >> 3, hh = pid & 7;
        const size_t kvb = ((size_t)(l * 64 + b) * 8 + hh) * (size_t)8192;
        if (t < 64) qv_s[pp][t] = bf2f(p.qT[b * 512 + hh * 64 + t]);
        __syncthreads();
        float s = -1e30f;
        if (t <= st && t < 128) {
          const uint4* kp = (const uint4*)(p.Kc + kvb + (size_t)t * 64);
          float sc = 0.f;
          #pragma unroll
          for (int j2 = 0; j2 < 8; ++j2) {
            const uint4 k4 = kp[j2];
            sc += qv_s[pp][j2*8+0] * bf2f((ushort_t)k4.x)
                + qv_s[pp][j2*8+1] * bf2f((ushort_t)(k4.x >> 16))
                + qv_s[pp][j2*8+2] * bf2f((ushort_t)k4.y)
                + qv_s[pp][j2*8+3] * bf2f((ushort_t)(k4.y >> 16))
                + qv_s[pp][j2*8+4] * bf2f((ushort_t)k4.z)
                + qv_s[pp][j2*8+5] * bf2f((ushort_t)(k4.z >> 16))
                + qv_s[pp][j2*8+6] * bf2f((ushort_t)k4.w)
                + qv_s[pp][j2*8+7] * bf2f((ushort_t)(k4.w >> 16));
          }
          s = sc;
        }
        red1[tid] = s; __syncthreads();
        for (int s2 = 128; s2 >= 1; s2 >>= 1) {
          if (t < s2) red1[tid] = fmaxf(red1[tid], red1[tid + s2]);
          __syncthreads();
        }
        const float mx = red1[pp * 256];
        __syncthreads();
        const float e = (t <= st && t < 128) ? expf(s - mx) : 0.f;
        if (t < 128) att_s[pp][t] = e;
        red1[tid] = e; __syncthreads();
        for (int s2 = 128; s2 >= 1; s2 >>= 1) {
          if (t < s2) red1[tid] += red1[tid + s2];
          __syncthreads();
        }
        if (t == 0) inv_s[pp] = 1.f / red1[pp * 256];
        __syncthreads();
        const int d = t & 63, tq = t >> 6;
        float o = 0.f;
        for (int tt = tq; tt <= st; tt += 4)
          o += att_s[pp][tt] * bf2f(p.Vc[kvb + (size_t)tt * 64 + d]);
        red1[tid] = o; __syncthreads();
        if (tid < 128) {
          const int p2 = tid >> 6, d2 = tid & 63;
          const int pid2 = bid * 2 + p2, b2 = pid2 >> 3, h2 = pid2 & 7;
          const float oo = (red1[p2*256 + d2] + red1[p2*256 + 64 + d2]
                          + red1[p2*256 + 128 + d2] + red1[p2*256 + 192 + d2]) * inv_s[p2];
          p.oT[b2 * 512 + h2 * 64 + d2] = f2bf(oo);
        }
      }
      g_arrive(gs, xcd, bt);
      if (slot < 8) w_pref<512>(p.wp + (size_t)l * 262144 + cbC * 32, wC);
      g_wait(gs, bt); ++bt;

      // ==== C: proj full-K + residual -> h1 (64 WGs: xcd owns 2 cb x 4 rb) ====
      if (slot < 8) {
        const int rb = slot & 3;
        stage_bf(p.oT, 512, rb * 16, 0, slab);
        __syncthreads();
        ACC_INIT
        gemm_fma(slab, wC, acc0, acc1);
        const float v = gemm_finish(acc0, acc1, redw);
        const int col = tid & 31, m = tid >> 5;
        const int gcol = cbC * 32 + col, row = rb * 16 + m;
        p.h1[row * 512 + gcol] = p.h0[row * 512 + gcol] + v + p.proj_b[l * 512 + gcol];
      }
      g_arrive(gs, xcd, bt);
      w_pref<2048>(p.wf + (size_t)l * 1048576 + cbD * 32, wD);
      g_wait(gs, bt); ++bt;

      // ==== D: LN2-stats + fc full-K + gelu -> gT (256 WGs: 8 cb x 4 rb per xcd) ====
      {
        const int rb = slot & 3;
        stats_ln(p.h1, p.ln2_w + l * 512, p.ln2_b + l * 512, rb, slab);
        __syncthreads();
        ACC_INIT
        gemm_fma(slab, wD, acc0, acc1);
        const float v = gemm_finish(acc0, acc1, redw);
        const int col = tid & 31, m = tid >> 5;
        const int gcol = cbD * 32 + col;
        const float x = v + p.fc_b[l * 2048 + gcol];
        p.gT[(size_t)(rb * 16 + m) * 2048 + gcol] =
            f2bf(0.5f * x * (1.f + erff(x * 0.70710678118654752f)));
      }
      g_arrive(gs, xcd, bt);
      if (slot < 8) w_pref<512>(p.wm + (size_t)l * 1048576 + cbC * 32, wE);
      g_wait(gs, bt); ++bt;

      // ==== E: mproj full-K (4 seq 512-chunks) + residual -> h0 (64 WGs) ====
      if (slot < 8) {
        const int rb = slot & 3;
        ACC_INIT
        for (int ch = 0; ch < 4; ++ch) {
          __syncthreads();
          stage_bf(p.gT, 2048, rb * 16, ch * 512, slab);
          __syncthreads();
          if (ch == 0) gemm_fma(slab, wE, acc0, acc1);
          else gemm_acc<512>(p.wm + (size_t)l * 1048576 + (size_t)(ch * 512) * 512 + cbC * 32,
                             slab, acc0, acc1);
        }
        const float v = gemm_finish(acc0, acc1, redw);
        const int col = tid & 31, m = tid >> 5;
        const int gcol = cbC * 32 + col, row = rb * 16 + m;
        p.h0[row * 512 + gcol] = p.h1[row * 512 + gcol] + v + p.mproj_b[l * 512 + gcol];
      }
      g_arrive(gs, xcd, bt);
      {
        const int nl = (l < L_ - 1) ? l + 1 : 0;
        if (slot < 24) w_pref<1536>(p.wq + (size_t)nl * 786432 + cbA * 32, wA);
      }
      g_wait(gs, bt); ++bt;
    } // layers

    // ==== F: lnf + head + ODE + out + embed(st+1) (64 WGs, one row each) ====
    if (slot < 8) {
      const int b = xcd * 8 + slot, t = tid;
      const float v = p.h0[b * 512 + t];
      red1[t] = v; red2[t] = v * v;
      __syncthreads();
      for (int s2 = 256; s2 >= 1; s2 >>= 1) {
        if (t < s2) { red1[t] += red1[t + s2]; red2[t] += red2[t + s2]; }
        __syncthreads();
      }
      const float mu = red1[0] * (1.f / 512.f);
      const float rs = rsqrtf(red2[0] * (1.f / 512.f) - mu * mu + 1e-5f);
      __syncthreads();
      const float hf = (v - mu) * rs * p.lnf_w[t] + p.lnf_b[t];
      red1[t] = hf * p.head_w[t * 2];
      red2[t] = hf * p.head_w[t * 2 + 1];
      __syncthreads();
      for (int s2 = 256; s2 >= 1; s2 >>= 1) {
        if (t < s2) { red1[t] += red1[t + s2]; red2[t] += red2[t + s2]; }
        __syncthreads();
      }
      if (t < 2) {
        const float un = ((t == 0) ? red1[0] : red2[0]) + p.head_b[t];
        const float a  = p.data[b * 4 + t];
        const float bb = p.data[b * 4 + 2 + t];
        const float yv = p.y[b * 2 + t];
        p.out[b * 256 + st * 2 + t] = yv;
        const float yn = yv - a * yv + bb * un;
        p.y[b * 2 + t] = yn;
        p.u[b * 2 + t] = un;
        bc[t] = yn; bc[2 + t] = un;
      }
      __syncthreads();
      if (st < T_ - 1) {
        const float e0 = p.r[b * 256 + (st + 1) * 2]     - bc[0];
        const float e1 = p.r[b * 256 + (st + 1) * 2 + 1] - bc[1];
        p.h0[b * 512 + t] = e0 * p.wte_w[t] + e1 * p.wte_w[512 + t]
                          + bc[2] * p.wte_w[1024 + t] + bc[3] * p.wte_w[1536 + t]
                          + p.wte_b[t] + p.wpe[(st + 1) * 512 + t];
      }
    }
    g_arrive(gs, xcd, bt);
    g_wait(gs, bt); ++bt;
  } // steps
}

extern "C" void kernel_launch(void* const* d_in, const int* in_sizes, int n_in,
                              void* d_out, int out_size, void* d_ws, size_t ws_size,
                              hipStream_t stream) {
  P p;
  p.data  =(const float*)d_in[0];  p.r      =(const float*)d_in[1];
  p.y_d   =(const float*)d_in[2];  p.wte_w  =(const float*)d_in[3];
  p.wte_b =(const float*)d_in[4];  p.wpe    =(const float*)d_in[5];
  p.ln1_w =(const float*)d_in[6];  p.ln1_b  =(const float*)d_in[7];
  p.qkv_w =(const float*)d_in[8];  p.qkv_b  =(const float*)d_in[9];
  p.proj_w=(const float*)d_in[10]; p.proj_b =(const float*)d_in[11];
  p.ln2_w =(const float*)d_in[12]; p.ln2_b  =(const float*)d_in[13];
  p.fc_w  =(const float*)d_in[14]; p.fc_b   =(const float*)d_in[15];
  p.mproj_w=(const float*)d_in[16];p.mproj_b=(const float*)d_in[17];
  p.lnf_w =(const float*)d_in[18]; p.lnf_b  =(const float*)d_in[19];
  p.head_w=(const float*)d_in[20]; p.head_b =(const float*)d_in[21];
  p.out = (float*)d_out;

  char* w = (char*)d_ws;
  size_t off = 0;
  p.sync=(u64*)(w+off);            off += 8192;
  p.y   =(float*)(w+off);          off += 512;
  p.u   =(float*)(w+off);          off += 512;
  p.h0  =(float*)(w+off);          off += (size_t)64*512*4;
  p.h1  =(float*)(w+off);          off += (size_t)64*512*4;
  p.qT  =(ushort_t*)(w+off);       off += (size_t)64*512*2;
  p.oT  =(ushort_t*)(w+off);       off += (size_t)64*512*2;
  p.gT  =(ushort_t*)(w+off);       off += (size_t)64*2048*2;
  p.wq  =(ushort_t*)(w+off);       off += (size_t)8*512*1536*2;
  p.wp  =(ushort_t*)(w+off);       off += (size_t)8*512*512*2;
  p.wf  =(ushort_t*)(w+off);       off += (size_t)8*512*2048*2;
  p.wm  =(ushort_t*)(w+off);       off += (size_t)8*2048*512*2;
  p.Kc  =(ushort_t*)(w+off);       off += (size_t)L_*64*8*T_*64*2;
  p.Vc  =(ushort_t*)(w+off);       off += (size_t)L_*64*8*T_*64*2;

  fprintf(stderr, "[gptloop] ws_size=%zu need=%zu\n", ws_size, off);
  if (ws_size < off) return;

  hipMemsetAsync(d_ws, 0, 8192, stream);
  hipLaunchKernelGGL(wconv, dim3(1024), dim3(256), 0, stream, p.qkv_w,  p.wq, 8*512*1536);
  hipLaunchKernelGGL(wconv, dim3(1024), dim3(256), 0, stream, p.proj_w, p.wp, 8*512*512);
  hipLaunchKernelGGL(wconv, dim3(1024), dim3(256), 0, stream, p.fc_w,   p.wf, 8*512*2048);
  hipLaunchKernelGGL(wconv, dim3(1024), dim3(256), 0, stream, p.mproj_w,p.wm, 8*2048*512);
  hipLaunchKernelGGL(gptloop, dim3(NWG), dim3(NT), 0, stream, p);
}

// Round 14
// 98094.867 us; speedup vs baseline: 1.0656x; 1.0656x over previous
//
#include <hip/hip_runtime.h>
#include <hip/hip_bf16.h>
#include <math.h>
#include <stdio.h>

#define NWG 256
#define NT  512
#define T_  128
#define L_  8
typedef unsigned short ushort_t;
typedef unsigned long long u64;

struct P {
  const float *data,*r,*y_d,*wte_w,*wte_b,*wpe,*ln1_w,*ln1_b,*qkv_w,*qkv_b,
              *proj_w,*proj_b,*ln2_w,*ln2_b,*fc_w,*fc_b,*mproj_w,*mproj_b,
              *lnf_w,*lnf_b,*head_w,*head_b;
  float *out, *y, *u, *h0, *h1;
  ushort_t *qT, *oT, *gT;                 // bf16 activations
  ushort_t *wq, *wp, *wf, *wm;            // bf16 weights (converted at launch)
  ushort_t *Kc, *Vc;
  u64 *sync;
};

__device__ __forceinline__ float bf2f(ushort_t u) {
  return __uint_as_float(((unsigned)u) << 16);
}
__device__ __forceinline__ ushort_t f2bf(float f) {
  __hip_bfloat16 b = __float2bfloat16(f);
  return *reinterpret_cast<ushort_t*>(&b);
}

// fp32 -> bf16 weight conversion (idempotent; replayed per graph launch).
__global__ void wconv(const float* __restrict__ src, ushort_t* __restrict__ dst, int n) {
  int i = blockIdx.x * blockDim.x + threadIdx.x;
  const int stride = gridDim.x * blockDim.x;
  for (; i < n; i += stride) dst[i] = f2bf(src[i]);
}

// ---- Barrier v4: flag-publish, split arrive/wait (r13 design, spill-safe use). ----
// gs[0]=gen; gs[8..15]=done[8] (one line); gs[16+x*16]=leaf[x].
// Leaf arrivals relaxed; leaf-last RELEASE-stores done[x]=bt (ONE wbL2/XCD —
// all 32 WGs' stores already sit in that L2 via __syncthreads vmcnt(0));
// leaf-lasts poll done[0..7], acquire-fence, idempotent fetch_max publish.
__device__ __forceinline__ void g_arrive(u64* gs, int xcd, u64 bt) {
  __syncthreads();
  if (threadIdx.x == 0) {
    const u64 lo = __hip_atomic_fetch_add(gs + 16 + xcd * 16, 1ULL,
                                          __ATOMIC_RELAXED, __HIP_MEMORY_SCOPE_AGENT);
    if (lo == 31ULL) {
      __hip_atomic_store(gs + 16 + xcd * 16, 0ULL, __ATOMIC_RELAXED, __HIP_MEMORY_SCOPE_AGENT);
      __hip_atomic_store(gs + 8 + xcd, bt, __ATOMIC_RELEASE, __HIP_MEMORY_SCOPE_AGENT);
      for (;;) {
        bool all = true;
        #pragma unroll
        for (int x = 0; x < 8; ++x)
          all &= (__hip_atomic_load(gs + 8 + x, __ATOMIC_RELAXED, __HIP_MEMORY_SCOPE_AGENT) >= bt);
        if (all) break;
        __builtin_amdgcn_s_sleep(1);
      }
      __builtin_amdgcn_fence(__ATOMIC_ACQUIRE, "agent");
      (void)__hip_atomic_fetch_max(gs, bt, __ATOMIC_RELEASE, __HIP_MEMORY_SCOPE_AGENT);
    }
  }
  // no trailing syncthreads: waves proceed to barrier-independent prefetch.
}

__device__ __forceinline__ void g_wait(u64* gs, u64 bt) {
  if (threadIdx.x == 0) {
    while (__hip_atomic_load(gs, __ATOMIC_RELAXED, __HIP_MEMORY_SCOPE_AGENT) < bt)
      __builtin_amdgcn_s_sleep(1);
    __builtin_amdgcn_fence(__ATOMIC_ACQUIRE, "agent");
  }
  __syncthreads();
}

// Bank-swizzle for slab[k][16] (r9-proven): word k*16 + (m ^ (((k>>1)&3)<<2)).
__device__ __forceinline__ int swz4(int k) { return ((k >> 1) & 3); }

// Stage slab[512][16] (swizzled) from bf16 row-major src rows of width W.
__device__ __forceinline__ void stage_bf(const ushort_t* __restrict__ src, int W,
                                         int row0, int k0, float* slab) {
  const int tid = threadIdx.x;
  const int m = tid >> 5, q = tid & 31;
  const ushort_t* sp = src + (size_t)(row0 + m) * W + k0;
  #pragma unroll
  for (int i = 0; i < 16; ++i) {
    const int k = q + i * 32;
    slab[k * 16 + (m ^ (swz4(k) << 2))] = bf2f(sp[k]);
  }
}

// Read 16 fp32 rows of h, per-row LN stats via 32-lane shfl, write
// normalized values into slab (swizzled).
__device__ __forceinline__ void stats_ln(const float* __restrict__ h,
                                         const float* __restrict__ lnw,
                                         const float* __restrict__ lnb,
                                         int rb, float* slab) {
  const int tid = threadIdx.x;
  const int m = tid >> 5, q = tid & 31;
  const float* hp = h + (size_t)(rb * 16 + m) * 512;
  float vv[16];
  float s = 0.f, s2 = 0.f;
  #pragma unroll
  for (int i = 0; i < 16; ++i) {
    const int k = q + i * 32;
    const float v = hp[k];
    vv[i] = v; s += v; s2 += v * v;
  }
  #pragma unroll
  for (int mk = 1; mk <= 16; mk <<= 1) { s += __shfl_xor(s, mk); s2 += __shfl_xor(s2, mk); }
  const float mu = s * (1.f / 512.f);
  const float rs = rsqrtf(s2 * (1.f / 512.f) - mu * mu + 1e-5f);
  #pragma unroll
  for (int i = 0; i < 16; ++i) {
    const int k = q + i * 32;
    slab[k * 16 + (m ^ (swz4(k) << 2))] = (vv[i] - mu) * rs * lnw[k] + lnb[k];
  }
}

#define FMA_ALL(W_, A_) \
  A_[0]+=W_*a0.x; A_[1]+=W_*a0.y; A_[2]+=W_*a0.z; A_[3]+=W_*a0.w; \
  A_[4]+=W_*a1.x; A_[5]+=W_*a1.y; A_[6]+=W_*a1.z; A_[7]+=W_*a1.w; \
  A_[8]+=W_*a2.x; A_[9]+=W_*a2.y; A_[10]+=W_*a2.z; A_[11]+=W_*a2.w; \
  A_[12]+=W_*a3.x; A_[13]+=W_*a3.y; A_[14]+=W_*a3.z; A_[15]+=W_*a3.w;

// Prefetch the WG's 16 weight dwords for one 512-k chunk (registers only).
template<int N>
__device__ __forceinline__ void w_pref(const ushort_t* __restrict__ Wbase, unsigned* w) {
  const int tid = threadIdx.x;
  const int wv = tid >> 6, lane = tid & 63;
  const int kq = lane >> 4, cp = lane & 15;
  const int r0 = wv * 64 + kq;
  const ushort_t* Wg = Wbase + (size_t)r0 * N + cp * 2;
  #pragma unroll
  for (int u = 0; u < 16; ++u)
    w[u] = *(const unsigned*)(Wg + (size_t)(u * 4) * N);
}

// FMA half of the chunk GEMM using prefetched weights.
__device__ __forceinline__ void gemm_fma(const float* __restrict__ slab,
                                         const unsigned* w, float* acc0, float* acc1) {
  const int tid = threadIdx.x;
  const int lane = tid & 63;
  const int wv = tid >> 6, kq = lane >> 4;
  const int r0 = wv * 64 + kq;
  #pragma unroll
  for (int u = 0; u < 16; ++u) {
    const int row = r0 + u * 4;
    const float4* b4 = (const float4*)(slab + row * 16);
    const int c4 = swz4(row);
    const float4 a0 = b4[0 ^ c4], a1 = b4[1 ^ c4], a2 = b4[2 ^ c4], a3 = b4[3 ^ c4];
    const float wx = bf2f((ushort_t)w[u]), wy = bf2f((ushort_t)(w[u] >> 16));
    FMA_ALL(wx, acc0)
    FMA_ALL(wy, acc1)
  }
}

template<int N>
__device__ __forceinline__ void gemm_acc(const ushort_t* __restrict__ Wbase,
                                         const float* __restrict__ slab,
                                         float* acc0, float* acc1) {
  unsigned w[16];
  w_pref<N>(Wbase, w);
  gemm_fma(slab, w, acc0, acc1);
}

// Cross-lane (kq) + cross-wave reduction; returns value for (col=tid&31, m=tid>>5).
__device__ __forceinline__ float gemm_finish(float* acc0, float* acc1, float* redw) {
  const int tid = threadIdx.x;
  const int wv = tid >> 6, lane = tid & 63;
  #pragma unroll
  for (int m = 0; m < 16; ++m) {
    acc0[m] += __shfl_xor(acc0[m], 16); acc1[m] += __shfl_xor(acc1[m], 16);
    acc0[m] += __shfl_xor(acc0[m], 32); acc1[m] += __shfl_xor(acc1[m], 32);
  }
  if (lane < 16) {
    float* rp = redw + wv * 528 + lane * 33;
    #pragma unroll
    for (int m = 0; m < 16; ++m) { rp[m] = acc0[m]; rp[16 + m] = acc1[m]; }
  }
  __syncthreads();
  const int col = tid & 31, m2 = tid >> 5;
  float s = 0.f;
  #pragma unroll
  for (int w2 = 0; w2 < 8; ++w2)
    s += redw[w2 * 528 + (col >> 1) * 33 + (col & 1) * 16 + m2];
  return s;
}

#define ACC_INIT float acc0[16], acc1[16]; \
  _Pragma("unroll") for (int m_ = 0; m_ < 16; ++m_) { acc0[m_] = 0.f; acc1[m_] = 0.f; }

__global__ __launch_bounds__(NT, 1) void gptloop(P p) {
  const int bid = blockIdx.x, tid = threadIdx.x;
  const int xcd = bid & 7, slot = bid >> 3;   // bid%8 = XCD (m09); slot 0..31
  u64* gs = p.sync;
  u64 bt = 1;

  __shared__ float slab[8192];
  __shared__ float redw[8 * 528];
  __shared__ float red1[512], red2[512];
  __shared__ float att_s[2][128];
  __shared__ float qv_s[2][64];
  __shared__ float inv_s[2];
  __shared__ float bc[4];

  unsigned wbuf[16];                          // single prefetch buffer (16 VGPRs)
  const int cbA = xcd * 6 + (slot >> 2);      // stage A col-block (slot<24)
  const int cbC = xcd * 2 + (slot >> 2);      // stage C/E col-block (slot<8)
  const int cbD = xcd * 8 + (slot >> 2);      // stage D col-block

  // ---- init: y/u + embed(st=0) -> h0 (64 WGs, one row each, XCD-spread) ----
  if (slot < 8) {
    const int b = xcd * 8 + slot, t = tid;
    const float y0 = p.y_d[b * 256], y1 = p.y_d[b * 256 + 1];
    const float e0 = p.r[b * 256] - y0, e1 = p.r[b * 256 + 1] - y1;
    p.h0[b * 512 + t] = e0 * p.wte_w[t] + e1 * p.wte_w[512 + t]
                      + 191.713f * p.wte_w[1024 + t] + 215.888f * p.wte_w[1536 + t]
                      + p.wte_b[t] + p.wpe[t];
    if (t < 2) {
      p.y[b * 2 + t] = t ? y1 : y0;
      p.u[b * 2 + t] = t ? 215.888f : 191.713f;
    }
  }
  g_arrive(gs, xcd, bt);
  if (slot < 24) w_pref<1536>(p.wq + cbA * 32, wbuf);
  g_wait(gs, bt); ++bt;

  for (int st = 0; st < T_; ++st) {
    for (int l = 0; l < L_; ++l) {
      // ==== A: LN1-stats + qkv full-K (192 WGs: xcd owns 6 cb x 4 rb) ====
      if (slot < 24) {
        const int rb = slot & 3;
        stats_ln(p.h0, p.ln1_w + l * 512, p.ln1_b + l * 512, rb, slab);
        __syncthreads();
        ACC_INIT
        gemm_fma(slab, wbuf, acc0, acc1);
        float v = gemm_finish(acc0, acc1, redw);
        const int col = tid & 31, m = tid >> 5;
        const int gcol = cbA * 32 + col;
        v += p.qkv_b[l * 1536 + gcol];
        const int part = gcol >> 9, head = (gcol & 511) >> 6, off = gcol & 63;
        const int b = rb * 16 + m;
        if (part == 0) {
          p.qT[b * 512 + gcol] = f2bf(v * 0.125f);   // fold 1/sqrt(HD)
        } else {
          ushort_t* dst = (part == 1) ? p.Kc : p.Vc;
          dst[((size_t)(l * 64 + b) * 8 + head) * 8192 + st * 64 + off] = f2bf(v);
        }
      }
      g_arrive(gs, xcd, bt);
      g_wait(gs, bt); ++bt;

      // ==== B: attention (256 WGs x 2 (b,h) pairs) -> oT ====
      {
        const int pp = tid >> 8, t = tid & 255;
        const int pid = bid * 2 + pp, b = pid >> 3, hh = pid & 7;
        const size_t kvb = ((size_t)(l * 64 + b) * 8 + hh) * (size_t)8192;
        if (t < 64) qv_s[pp][t] = bf2f(p.qT[b * 512 + hh * 64 + t]);
        __syncthreads();
        float s = -1e30f;
        if (t <= st && t < 128) {
          const uint4* kp = (const uint4*)(p.Kc + kvb + (size_t)t * 64);
          float sc = 0.f;
          #pragma unroll
          for (int j2 = 0; j2 < 8; ++j2) {
            const uint4 k4 = kp[j2];
            sc += qv_s[pp][j2*8+0] * bf2f((ushort_t)k4.x)
                + qv_s[pp][j2*8+1] * bf2f((ushort_t)(k4.x >> 16))
                + qv_s[pp][j2*8+2] * bf2f((ushort_t)k4.y)
                + qv_s[pp][j2*8+3] * bf2f((ushort_t)(k4.y >> 16))
                + qv_s[pp][j2*8+4] * bf2f((ushort_t)k4.z)
                + qv_s[pp][j2*8+5] * bf2f((ushort_t)(k4.z >> 16))
                + qv_s[pp][j2*8+6] * bf2f((ushort_t)k4.w)
                + qv_s[pp][j2*8+7] * bf2f((ushort_t)(k4.w >> 16));
          }
          s = sc;
        }
        red1[tid] = s; __syncthreads();
        for (int s2 = 128; s2 >= 1; s2 >>= 1) {
          if (t < s2) red1[tid] = fmaxf(red1[tid], red1[tid + s2]);
          __syncthreads();
        }
        const float mx = red1[pp * 256];
        __syncthreads();
        const float e = (t <= st && t < 128) ? expf(s - mx) : 0.f;
        if (t < 128) att_s[pp][t] = e;
        red1[tid] = e; __syncthreads();
        for (int s2 = 128; s2 >= 1; s2 >>= 1) {
          if (t < s2) red1[tid] += red1[tid + s2];
          __syncthreads();
        }
        if (t == 0) inv_s[pp] = 1.f / red1[pp * 256];
        __syncthreads();
        const int d = t & 63, tq = t >> 6;
        float o = 0.f;
        for (int tt = tq; tt <= st; tt += 4)
          o += att_s[pp][tt] * bf2f(p.Vc[kvb + (size_t)tt * 64 + d]);
        red1[tid] = o; __syncthreads();
        if (tid < 128) {
          const int p2 = tid >> 6, d2 = tid & 63;
          const int pid2 = bid * 2 + p2, b2 = pid2 >> 3, h2 = pid2 & 7;
          const float oo = (red1[p2*256 + d2] + red1[p2*256 + 64 + d2]
                          + red1[p2*256 + 128 + d2] + red1[p2*256 + 192 + d2]) * inv_s[p2];
          p.oT[b2 * 512 + h2 * 64 + d2] = f2bf(oo);
        }
      }
      g_arrive(gs, xcd, bt);
      if (slot < 8) w_pref<512>(p.wp + (size_t)l * 262144 + cbC * 32, wbuf);
      g_wait(gs, bt); ++bt;

      // ==== C: proj full-K + residual -> h1 (64 WGs: xcd owns 2 cb x 4 rb) ====
      if (slot < 8) {
        const int rb = slot & 3;
        stage_bf(p.oT, 512, rb * 16, 0, slab);
        __syncthreads();
        ACC_INIT
        gemm_fma(slab, wbuf, acc0, acc1);
        const float v = gemm_finish(acc0, acc1, redw);
        const int col = tid & 31, m = tid >> 5;
        const int gcol = cbC * 32 + col, row = rb * 16 + m;
        p.h1[row * 512 + gcol] = p.h0[row * 512 + gcol] + v + p.proj_b[l * 512 + gcol];
      }
      g_arrive(gs, xcd, bt);
      w_pref<2048>(p.wf + (size_t)l * 1048576 + cbD * 32, wbuf);
      g_wait(gs, bt); ++bt;

      // ==== D: LN2-stats + fc full-K + gelu -> gT (256 WGs: 8 cb x 4 rb per xcd) ====
      {
        const int rb = slot & 3;
        stats_ln(p.h1, p.ln2_w + l * 512, p.ln2_b + l * 512, rb, slab);
        __syncthreads();
        ACC_INIT
        gemm_fma(slab, wbuf, acc0, acc1);
        const float v = gemm_finish(acc0, acc1, redw);
        const int col = tid & 31, m = tid >> 5;
        const int gcol = cbD * 32 + col;
        const float x = v + p.fc_b[l * 2048 + gcol];
        p.gT[(size_t)(rb * 16 + m) * 2048 + gcol] =
            f2bf(0.5f * x * (1.f + erff(x * 0.70710678118654752f)));
      }
      g_arrive(gs, xcd, bt);
      if (slot < 8) w_pref<512>(p.wm + (size_t)l * 1048576 + cbC * 32, wbuf);
      g_wait(gs, bt); ++bt;

      // ==== E: mproj full-K (4 seq 512-chunks) + residual -> h0 (64 WGs) ====
      if (slot < 8) {
        const int rb = slot & 3;
        ACC_INIT
        for (int ch = 0; ch < 4; ++ch) {
          __syncthreads();
          stage_bf(p.gT, 2048, rb * 16, ch * 512, slab);
          __syncthreads();
          if (ch == 0) gemm_fma(slab, wbuf, acc0, acc1);
          else gemm_acc<512>(p.wm + (size_t)l * 1048576 + (size_t)(ch * 512) * 512 + cbC * 32,
                             slab, acc0, acc1);
        }
        const float v = gemm_finish(acc0, acc1, redw);
        const int col = tid & 31, m = tid >> 5;
        const int gcol = cbC * 32 + col, row = rb * 16 + m;
        p.h0[row * 512 + gcol] = p.h1[row * 512 + gcol] + v + p.mproj_b[l * 512 + gcol];
      }
      g_arrive(gs, xcd, bt);
      {
        const int nl = (l < L_ - 1) ? l + 1 : 0;
        if (slot < 24) w_pref<1536>(p.wq + (size_t)nl * 786432 + cbA * 32, wbuf);
      }
      g_wait(gs, bt); ++bt;
    } // layers

    // ==== F: lnf + head + ODE + out + embed(st+1) (64 WGs, one row each) ====
    // (wbuf holds next step's qkv weights; F does not touch it.)
    if (slot < 8) {
      const int b = xcd * 8 + slot, t = tid;
      const float v = p.h0[b * 512 + t];
      red1[t] = v; red2[t] = v * v;
      __syncthreads();
      for (int s2 = 256; s2 >= 1; s2 >>= 1) {
        if (t < s2) { red1[t] += red1[t + s2]; red2[t] += red2[t + s2]; }
        __syncthreads();
      }
      const float mu = red1[0] * (1.f / 512.f);
      const float rs = rsqrtf(red2[0] * (1.f / 512.f) - mu * mu + 1e-5f);
      __syncthreads();
      const float hf = (v - mu) * rs * p.lnf_w[t] + p.lnf_b[t];
      red1[t] = hf * p.head_w[t * 2];
      red2[t] = hf * p.head_w[t * 2 + 1];
      __syncthreads();
      for (int s2 = 256; s2 >= 1; s2 >>= 1) {
        if (t < s2) { red1[t] += red1[t + s2]; red2[t] += red2[t + s2]; }
        __syncthreads();
      }
      if (t < 2) {
        const float un = ((t == 0) ? red1[0] : red2[0]) + p.head_b[t];
        const float a  = p.data[b * 4 + t];
        const float bb = p.data[b * 4 + 2 + t];
        const float yv = p.y[b * 2 + t];
        p.out[b * 256 + st * 2 + t] = yv;
        const float yn = yv - a * yv + bb * un;
        p.y[b * 2 + t] = yn;
        p.u[b * 2 + t] = un;
        bc[t] = yn; bc[2 + t] = un;
      }
      __syncthreads();
      if (st < T_ - 1) {
        const float e0 = p.r[b * 256 + (st + 1) * 2]     - bc[0];
        const float e1 = p.r[b * 256 + (st + 1) * 2 + 1] - bc[1];
        p.h0[b * 512 + t] = e0 * p.wte_w[t] + e1 * p.wte_w[512 + t]
                          + bc[2] * p.wte_w[1024 + t] + bc[3] * p.wte_w[1536 + t]
                          + p.wte_b[t] + p.wpe[(st + 1) * 512 + t];
      }
    }
    g_arrive(gs, xcd, bt);
    g_wait(gs, bt); ++bt;
  } // steps
}

extern "C" void kernel_launch(void* const* d_in, const int* in_sizes, int n_in,
                              void* d_out, int out_size, void* d_ws, size_t ws_size,
                              hipStream_t stream) {
  P p;
  p.data  =(const float*)d_in[0];  p.r      =(const float*)d_in[1];
  p.y_d   =(const float*)d_in[2];  p.wte_w  =(const float*)d_in[3];
  p.wte_b =(const float*)d_in[4];  p.wpe    =(const float*)d_in[5];
  p.ln1_w =(const float*)d_in[6];  p.ln1_b  =(const float*)d_in[7];
  p.qkv_w =(const float*)d_in[8];  p.qkv_b  =(const float*)d_in[9];
  p.proj_w=(const float*)d_in[10]; p.proj_b =(const float*)d_in[11];
  p.ln2_w =(const float*)d_in[12]; p.ln2_b  =(const float*)d_in[13];
  p.fc_w  =(const float*)d_in[14]; p.fc_b   =(const float*)d_in[15];
  p.mproj_w=(const float*)d_in[16];p.mproj_b=(const float*)d_in[17];
  p.lnf_w =(const float*)d_in[18]; p.lnf_b  =(const float*)d_in[19];
  p.head_w=(const float*)d_in[20]; p.head_b =(const float*)d_in[21];
  p.out = (float*)d_out;

  char* w = (char*)d_ws;
  size_t off = 0;
  p.sync=(u64*)(w+off);            off += 8192;
  p.y   =(float*)(w+off);          off += 512;
  p.u   =(float*)(w+off);          off += 512;
  p.h0  =(float*)(w+off);          off += (size_t)64*512*4;
  p.h1  =(float*)(w+off);          off += (size_t)64*512*4;
  p.qT  =(ushort_t*)(w+off);       off += (size_t)64*512*2;
  p.oT  =(ushort_t*)(w+off);       off += (size_t)64*512*2;
  p.gT  =(ushort_t*)(w+off);       off += (size_t)64*2048*2;
  p.wq  =(ushort_t*)(w+off);       off += (size_t)8*512*1536*2;
  p.wp  =(ushort_t*)(w+off);       off += (size_t)8*512*512*2;
  p.wf  =(ushort_t*)(w+off);       off += (size_t)8*512*2048*2;
  p.wm  =(ushort_t*)(w+off);       off += (size_t)8*2048*512*2;
  p.Kc  =(ushort_t*)(w+off);       off += (size_t)L_*64*8*T_*64*2;
  p.Vc  =(ushort_t*)(w+off);       off += (size_t)L_*64*8*T_*64*2;

  fprintf(stderr, "[gptloop] ws_size=%zu need=%zu\n", ws_size, off);
  if (ws_size < off) return;

  hipMemsetAsync(d_ws, 0, 8192, stream);
  hipLaunchKernelGGL(wconv, dim3(1024), dim3(256), 0, stream, p.qkv_w,  p.wq, 8*512*1536);
  hipLaunchKernelGGL(wconv, dim3(1024), dim3(256), 0, stream, p.proj_w, p.wp, 8*512*512);
  hipLaunchKernelGGL(wconv, dim3(1024), dim3(256), 0, stream, p.fc_w,   p.wf, 8*512*2048);
  hipLaunchKernelGGL(wconv, dim3(1024), dim3(256), 0, stream, p.mproj_w,p.wm, 8*2048*512);
  hipLaunchKernelGGL(gptloop, dim3(NWG), dim3(NT), 0, stream, p);
}

// Round 15
// 68188.922 us; speedup vs baseline: 1.5329x; 1.4386x over previous
//
#include <hip/hip_runtime.h>
#include <hip/hip_bf16.h>
#include <math.h>
#include <stdio.h>

#define NWG 256
#define NT  512
#define T_  128
#define L_  8
typedef unsigned short ushort_t;
typedef unsigned long long u64;

struct P {
  const float *data,*r,*y_d,*wte_w,*wte_b,*wpe,*ln1_w,*ln1_b,*qkv_w,*qkv_b,
              *proj_w,*proj_b,*ln2_w,*ln2_b,*fc_w,*fc_b,*mproj_w,*mproj_b,
              *lnf_w,*lnf_b,*head_w,*head_b;
  float *out, *y, *u, *h0, *h1;
  ushort_t *qT, *oT, *gT;                 // bf16 activations
  ushort_t *wq, *wp, *wf, *wm;            // bf16 weights (converted at launch)
  ushort_t *Kc, *Vc;
  u64 *sync;
};

__device__ __forceinline__ float bf2f(ushort_t u) {
  return __uint_as_float(((unsigned)u) << 16);
}
__device__ __forceinline__ ushort_t f2bf(float f) {
  __hip_bfloat16 b = __float2bfloat16(f);
  return *reinterpret_cast<ushort_t*>(&b);
}

// fp32 -> bf16 weight conversion (idempotent; replayed per graph launch).
__global__ void wconv(const float* __restrict__ src, ushort_t* __restrict__ dst, int n) {
  int i = blockIdx.x * blockDim.x + threadIdx.x;
  const int stride = gridDim.x * blockDim.x;
  for (; i < n; i += stride) dst[i] = f2bf(src[i]);
}

// Pair-local barrier (64 WGs = 2 XCDs x 32): v3 cache-op-minimal design
// (r12-proven semantics), scoped to one XCD pair. Leaf arrivals RELAXED
// (stores already in local L2 via __syncthreads vmcnt(0)); leaf-last does
// ONE RELEASE root RMW (wbL2 for the whole XCD); root-last bumps gen
// RELEASE; waiters poll RELAXED + one ACQUIRE on wake.
// Root chain depth 2 (was 8); convoy scope 64 WGs (was 256).
__device__ __forceinline__ void gbar(u64* gs, int lf) {
  __syncthreads();
  if (threadIdx.x == 0) {
    u64* leaf = gs + lf * 16;
    u64* root = gs + 32;
    u64* gen  = gs + 48;
    const u64 g0 = __hip_atomic_load(gen, __ATOMIC_RELAXED, __HIP_MEMORY_SCOPE_AGENT);
    const u64 lo = __hip_atomic_fetch_add(leaf, 1ULL, __ATOMIC_RELAXED, __HIP_MEMORY_SCOPE_AGENT);
    if (lo == 31ULL) {
      __hip_atomic_store(leaf, 0ULL, __ATOMIC_RELAXED, __HIP_MEMORY_SCOPE_AGENT);
      const u64 ro = __hip_atomic_fetch_add(root, 1ULL, __ATOMIC_RELEASE, __HIP_MEMORY_SCOPE_AGENT);
      if (ro == 1ULL) {
        __hip_atomic_store(root, 0ULL, __ATOMIC_RELAXED, __HIP_MEMORY_SCOPE_AGENT);
        __hip_atomic_fetch_add(gen, 1ULL, __ATOMIC_RELEASE, __HIP_MEMORY_SCOPE_AGENT);
      }
    }
    while (__hip_atomic_load(gen, __ATOMIC_RELAXED, __HIP_MEMORY_SCOPE_AGENT) == g0)
      __builtin_amdgcn_s_sleep(2);
    (void)__hip_atomic_load(gen, __ATOMIC_ACQUIRE, __HIP_MEMORY_SCOPE_AGENT);
  }
  __syncthreads();
}

// Bank-swizzle for slab[k][16] (r9-proven): word k*16 + (m ^ (((k>>1)&3)<<2)).
__device__ __forceinline__ int swz4(int k) { return ((k >> 1) & 3); }

// Stage slab[512][16] (swizzled) from bf16 row-major src rows of width W.
__device__ __forceinline__ void stage_bf(const ushort_t* __restrict__ src, int W,
                                         int row0, int k0, float* slab) {
  const int tid = threadIdx.x;
  const int m = tid >> 5, q = tid & 31;
  const ushort_t* sp = src + (size_t)(row0 + m) * W + k0;
  #pragma unroll
  for (int i = 0; i < 16; ++i) {
    const int k = q + i * 32;
    slab[k * 16 + (m ^ (swz4(k) << 2))] = bf2f(sp[k]);
  }
}

// Read 16 fp32 rows of h, per-row LN stats via 32-lane shfl, write
// normalized values into slab (swizzled).
__device__ __forceinline__ void stats_ln(const float* __restrict__ h,
                                         const float* __restrict__ lnw,
                                         const float* __restrict__ lnb,
                                         int rb, float* slab) {
  const int tid = threadIdx.x;
  const int m = tid >> 5, q = tid & 31;
  const float* hp = h + (size_t)(rb * 16 + m) * 512;
  float vv[16];
  float s = 0.f, s2 = 0.f;
  #pragma unroll
  for (int i = 0; i < 16; ++i) {
    const int k = q + i * 32;
    const float v = hp[k];
    vv[i] = v; s += v; s2 += v * v;
  }
  #pragma unroll
  for (int mk = 1; mk <= 16; mk <<= 1) { s += __shfl_xor(s, mk); s2 += __shfl_xor(s2, mk); }
  const float mu = s * (1.f / 512.f);
  const float rs = rsqrtf(s2 * (1.f / 512.f) - mu * mu + 1e-5f);
  #pragma unroll
  for (int i = 0; i < 16; ++i) {
    const int k = q + i * 32;
    slab[k * 16 + (m ^ (swz4(k) << 2))] = (vv[i] - mu) * rs * lnw[k] + lnb[k];
  }
}

#define FMA_ALL(W_, A_) \
  A_[0]+=W_*a0.x; A_[1]+=W_*a0.y; A_[2]+=W_*a0.z; A_[3]+=W_*a0.w; \
  A_[4]+=W_*a1.x; A_[5]+=W_*a1.y; A_[6]+=W_*a1.z; A_[7]+=W_*a1.w; \
  A_[8]+=W_*a2.x; A_[9]+=W_*a2.y; A_[10]+=W_*a2.z; A_[11]+=W_*a2.w; \
  A_[12]+=W_*a3.x; A_[13]+=W_*a3.y; A_[14]+=W_*a3.z; A_[15]+=W_*a3.w;

// Accumulate one 512-k chunk: acc[2cols][16rows] += slab(512x16) @ W(512xN).
// lane = kq(lane>>4, 4-way k) x cp(lane&15, 16 col-pairs = 64B W segments);
// all 16 weight loads issued up-front. (r12-proven, loads inline — no
// cross-barrier register state, no spill.)
template<int N>
__device__ __forceinline__ void gemm_acc(const ushort_t* __restrict__ Wbase,
                                         const float* __restrict__ slab,
                                         float* acc0, float* acc1) {
  const int tid = threadIdx.x;
  const int wv = tid >> 6, lane = tid & 63;
  const int kq = lane >> 4, cp = lane & 15;
  const int r0 = wv * 64 + kq;
  const ushort_t* Wg = Wbase + (size_t)r0 * N + cp * 2;
  unsigned w[16];
  #pragma unroll
  for (int u = 0; u < 16; ++u)
    w[u] = *(const unsigned*)(Wg + (size_t)(u * 4) * N);
  #pragma unroll
  for (int u = 0; u < 16; ++u) {
    const int row = r0 + u * 4;
    const float4* b4 = (const float4*)(slab + row * 16);
    const int c4 = swz4(row);
    const float4 a0 = b4[0 ^ c4], a1 = b4[1 ^ c4], a2 = b4[2 ^ c4], a3 = b4[3 ^ c4];
    const float wx = bf2f((ushort_t)w[u]), wy = bf2f((ushort_t)(w[u] >> 16));
    FMA_ALL(wx, acc0)
    FMA_ALL(wy, acc1)
  }
}

// Cross-lane (kq) + cross-wave reduction; returns value for (col=tid&31, m=tid>>5).
__device__ __forceinline__ float gemm_finish(float* acc0, float* acc1, float* redw) {
  const int tid = threadIdx.x;
  const int wv = tid >> 6, lane = tid & 63;
  #pragma unroll
  for (int m = 0; m < 16; ++m) {
    acc0[m] += __shfl_xor(acc0[m], 16); acc1[m] += __shfl_xor(acc1[m], 16);
    acc0[m] += __shfl_xor(acc0[m], 32); acc1[m] += __shfl_xor(acc1[m], 32);
  }
  if (lane < 16) {
    float* rp = redw + wv * 528 + lane * 33;
    #pragma unroll
    for (int m = 0; m < 16; ++m) { rp[m] = acc0[m]; rp[16 + m] = acc1[m]; }
  }
  __syncthreads();
  const int col = tid & 31, m2 = tid >> 5;
  float s = 0.f;
  #pragma unroll
  for (int w2 = 0; w2 < 8; ++w2)
    s += redw[w2 * 528 + (col >> 1) * 33 + (col & 1) * 16 + m2];
  return s;
}

#define ACC_INIT float acc0[16], acc1[16]; \
  _Pragma("unroll") for (int m_ = 0; m_ < 16; ++m_) { acc0[m_] = 0.f; acc1[m_] = 0.f; }

__global__ __launch_bounds__(NT, 1) void gptloop(P p) {
  const int bid = blockIdx.x, tid = threadIdx.x;
  const int xcd = bid & 7;                    // bid%8 = XCD (m09)
  const int pr  = xcd >> 1;                   // XCD pair 0..3 — owns 16 rows
  const int lf  = bid & 1;                    // leaf (XCD within pair)
  const int gw  = ((bid >> 3) << 1) | lf;     // 0..63 within pair
  u64* gs = p.sync + pr * 512;                // 4KB sync region per pair

  __shared__ float slab[8192];
  __shared__ float redw[8 * 528];
  __shared__ float red1[512], red2[512];
  __shared__ float att_s[2][128];
  __shared__ float qv_s[2][64];
  __shared__ float inv_s[2];
  __shared__ float bc[4];

  // ---- init: y/u + embed(st=0) -> h0 (16 WGs per pair, one row each) ----
  if (gw < 16) {
    const int b = pr * 16 + gw, t = tid;
    const float y0 = p.y_d[b * 256], y1 = p.y_d[b * 256 + 1];
    const float e0 = p.r[b * 256] - y0, e1 = p.r[b * 256 + 1] - y1;
    p.h0[b * 512 + t] = e0 * p.wte_w[t] + e1 * p.wte_w[512 + t]
                      + 191.713f * p.wte_w[1024 + t] + 215.888f * p.wte_w[1536 + t]
                      + p.wte_b[t] + p.wpe[t];
    if (t < 2) {
      p.y[b * 2 + t] = t ? y1 : y0;
      p.u[b * 2 + t] = t ? 215.888f : 191.713f;
    }
  }
  gbar(gs, lf);

  for (int st = 0; st < T_; ++st) {
    for (int l = 0; l < L_; ++l) {
      // ==== A: LN1-stats + qkv full-K (48 WGs/pair x 32 cols, rows = pair's 16) ====
      if (gw < 48) {
        const int cb = gw;
        stats_ln(p.h0, p.ln1_w + l * 512, p.ln1_b + l * 512, pr, slab);
        __syncthreads();
        ACC_INIT
        gemm_acc<1536>(p.wq + (size_t)l * 786432 + cb * 32, slab, acc0, acc1);
        float v = gemm_finish(acc0, acc1, redw);
        const int col = tid & 31, m = tid >> 5;
        const int gcol = cb * 32 + col;
        v += p.qkv_b[l * 1536 + gcol];
        const int part = gcol >> 9, head = (gcol & 511) >> 6, off = gcol & 63;
        const int b = pr * 16 + m;
        if (part == 0) {
          p.qT[b * 512 + gcol] = f2bf(v * 0.125f);   // fold 1/sqrt(HD)
        } else {
          ushort_t* dst = (part == 1) ? p.Kc : p.Vc;
          dst[((size_t)(l * 64 + b) * 8 + head) * 8192 + st * 64 + off] = f2bf(v);
        }
      }
      gbar(gs, lf);

      // ==== B: attention (64 WGs/pair x 2 (b,h) pairs) -> oT ====
      {
        const int pp = tid >> 8, t = tid & 255;
        const int pidl = gw * 2 + pp;                   // 0..127 within pair
        const int b = pr * 16 + (pidl >> 3), hh = pidl & 7;
        const size_t kvb = ((size_t)(l * 64 + b) * 8 + hh) * (size_t)8192;
        if (t < 64) qv_s[pp][t] = bf2f(p.qT[b * 512 + hh * 64 + t]);
        __syncthreads();
        float s = -1e30f;
        if (t <= st && t < 128) {
          const uint4* kp = (const uint4*)(p.Kc + kvb + (size_t)t * 64);
          float sc = 0.f;
          #pragma unroll
          for (int j2 = 0; j2 < 8; ++j2) {
            const uint4 k4 = kp[j2];
            sc += qv_s[pp][j2*8+0] * bf2f((ushort_t)k4.x)
                + qv_s[pp][j2*8+1] * bf2f((ushort_t)(k4.x >> 16))
                + qv_s[pp][j2*8+2] * bf2f((ushort_t)k4.y)
                + qv_s[pp][j2*8+3] * bf2f((ushort_t)(k4.y >> 16))
                + qv_s[pp][j2*8+4] * bf2f((ushort_t)k4.z)
                + qv_s[pp][j2*8+5] * bf2f((ushort_t)(k4.z >> 16))
                + qv_s[pp][j2*8+6] * bf2f((ushort_t)k4.w)
                + qv_s[pp][j2*8+7] * bf2f((ushort_t)(k4.w >> 16));
          }
          s = sc;
        }
        red1[tid] = s; __syncthreads();
        for (int s2 = 128; s2 >= 1; s2 >>= 1) {
          if (t < s2) red1[tid] = fmaxf(red1[tid], red1[tid + s2]);
          __syncthreads();
        }
        const float mx = red1[pp * 256];
        __syncthreads();
        const float e = (t <= st && t < 128) ? expf(s - mx) : 0.f;
        if (t < 128) att_s[pp][t] = e;
        red1[tid] = e; __syncthreads();
        for (int s2 = 128; s2 >= 1; s2 >>= 1) {
          if (t < s2) red1[tid] += red1[tid + s2];
          __syncthreads();
        }
        if (t == 0) inv_s[pp] = 1.f / red1[pp * 256];
        __syncthreads();
        const int d = t & 63, tq = t >> 6;
        float o = 0.f;
        for (int tt = tq; tt <= st; tt += 4)
          o += att_s[pp][tt] * bf2f(p.Vc[kvb + (size_t)tt * 64 + d]);
        red1[tid] = o; __syncthreads();
        if (tid < 128) {
          const int p2 = tid >> 6, d2 = tid & 63;
          const int pidl2 = gw * 2 + p2;
          const int b2 = pr * 16 + (pidl2 >> 3), h2 = pidl2 & 7;
          const float oo = (red1[p2*256 + d2] + red1[p2*256 + 64 + d2]
                          + red1[p2*256 + 128 + d2] + red1[p2*256 + 192 + d2]) * inv_s[p2];
          p.oT[b2 * 512 + h2 * 64 + d2] = f2bf(oo);
        }
      }
      gbar(gs, lf);

      // ==== C: proj full-K + residual -> h1 (16 WGs/pair x 32 cols) ====
      if (gw < 16) {
        const int cb = gw;
        stage_bf(p.oT, 512, pr * 16, 0, slab);
        __syncthreads();
        ACC_INIT
        gemm_acc<512>(p.wp + (size_t)l * 262144 + cb * 32, slab, acc0, acc1);
        const float v = gemm_finish(acc0, acc1, redw);
        const int col = tid & 31, m = tid >> 5;
        const int gcol = cb * 32 + col, row = pr * 16 + m;
        p.h1[row * 512 + gcol] = p.h0[row * 512 + gcol] + v + p.proj_b[l * 512 + gcol];
      }
      gbar(gs, lf);

      // ==== D: LN2-stats + fc full-K + gelu -> gT (64 WGs/pair x 32 cols) ====
      {
        const int cb = gw;
        stats_ln(p.h1, p.ln2_w + l * 512, p.ln2_b + l * 512, pr, slab);
        __syncthreads();
        ACC_INIT
        gemm_acc<2048>(p.wf + (size_t)l * 1048576 + cb * 32, slab, acc0, acc1);
        const float v = gemm_finish(acc0, acc1, redw);
        const int col = tid & 31, m = tid >> 5;
        const int gcol = cb * 32 + col;
        const float x = v + p.fc_b[l * 2048 + gcol];
        p.gT[(size_t)(pr * 16 + m) * 2048 + gcol] =
            f2bf(0.5f * x * (1.f + erff(x * 0.70710678118654752f)));
      }
      gbar(gs, lf);

      // ==== E: mproj full-K (4 seq 512-chunks) + residual -> h0 (16 WGs/pair) ====
      if (gw < 16) {
        const int cb = gw;
        ACC_INIT
        for (int ch = 0; ch < 4; ++ch) {
          __syncthreads();
          stage_bf(p.gT, 2048, pr * 16, ch * 512, slab);
          __syncthreads();
          gemm_acc<512>(p.wm + (size_t)l * 1048576 + (size_t)(ch * 512) * 512 + cb * 32,
                        slab, acc0, acc1);
        }
        const float v = gemm_finish(acc0, acc1, redw);
        const int col = tid & 31, m = tid >> 5;
        const int gcol = cb * 32 + col, row = pr * 16 + m;
        p.h0[row * 512 + gcol] = p.h1[row * 512 + gcol] + v + p.mproj_b[l * 512 + gcol];
      }
      gbar(gs, lf);
    } // layers

    // ==== F: lnf + head + ODE + out + embed(st+1) (16 WGs/pair, one row each) ====
    if (gw < 16) {
      const int b = pr * 16 + gw, t = tid;
      const float v = p.h0[b * 512 + t];
      red1[t] = v; red2[t] = v * v;
      __syncthreads();
      for (int s2 = 256; s2 >= 1; s2 >>= 1) {
        if (t < s2) { red1[t] += red1[t + s2]; red2[t] += red2[t + s2]; }
        __syncthreads();
      }
      const float mu = red1[0] * (1.f / 512.f);
      const float rs = rsqrtf(red2[0] * (1.f / 512.f) - mu * mu + 1e-5f);
      __syncthreads();
      const float hf = (v - mu) * rs * p.lnf_w[t] + p.lnf_b[t];
      red1[t] = hf * p.head_w[t * 2];
      red2[t] = hf * p.head_w[t * 2 + 1];
      __syncthreads();
      for (int s2 = 256; s2 >= 1; s2 >>= 1) {
        if (t < s2) { red1[t] += red1[t + s2]; red2[t] += red2[t + s2]; }
        __syncthreads();
      }
      if (t < 2) {
        const float un = ((t == 0) ? red1[0] : red2[0]) + p.head_b[t];
        const float a  = p.data[b * 4 + t];
        const float bb = p.data[b * 4 + 2 + t];
        const float yv = p.y[b * 2 + t];
        p.out[b * 256 + st * 2 + t] = yv;
        const float yn = yv - a * yv + bb * un;
        p.y[b * 2 + t] = yn;
        p.u[b * 2 + t] = un;
        bc[t] = yn; bc[2 + t] = un;
      }
      __syncthreads();
      if (st < T_ - 1) {
        const float e0 = p.r[b * 256 + (st + 1) * 2]     - bc[0];
        const float e1 = p.r[b * 256 + (st + 1) * 2 + 1] - bc[1];
        p.h0[b * 512 + t] = e0 * p.wte_w[t] + e1 * p.wte_w[512 + t]
                          + bc[2] * p.wte_w[1024 + t] + bc[3] * p.wte_w[1536 + t]
                          + p.wte_b[t] + p.wpe[(st + 1) * 512 + t];
      }
    }
    gbar(gs, lf);
  } // steps
}

extern "C" void kernel_launch(void* const* d_in, const int* in_sizes, int n_in,
                              void* d_out, int out_size, void* d_ws, size_t ws_size,
                              hipStream_t stream) {
  P p;
  p.data  =(const float*)d_in[0];  p.r      =(const float*)d_in[1];
  p.y_d   =(const float*)d_in[2];  p.wte_w  =(const float*)d_in[3];
  p.wte_b =(const float*)d_in[4];  p.wpe    =(const float*)d_in[5];
  p.ln1_w =(const float*)d_in[6];  p.ln1_b  =(const float*)d_in[7];
  p.qkv_w =(const float*)d_in[8];  p.qkv_b  =(const float*)d_in[9];
  p.proj_w=(const float*)d_in[10]; p.proj_b =(const float*)d_in[11];
  p.ln2_w =(const float*)d_in[12]; p.ln2_b  =(const float*)d_in[13];
  p.fc_w  =(const float*)d_in[14]; p.fc_b   =(const float*)d_in[15];
  p.mproj_w=(const float*)d_in[16];p.mproj_b=(const float*)d_in[17];
  p.lnf_w =(const float*)d_in[18]; p.lnf_b  =(const float*)d_in[19];
  p.head_w=(const float*)d_in[20]; p.head_b =(const float*)d_in[21];
  p.out = (float*)d_out;

  char* w = (char*)d_ws;
  size_t off = 0;
  p.sync=(u64*)(w+off);            off += 16384;   // 4KB per pair x 4
  p.y   =(float*)(w+off);          off += 512;
  p.u   =(float*)(w+off);          off += 512;
  p.h0  =(float*)(w+off);          off += (size_t)64*512*4;
  p.h1  =(float*)(w+off);          off += (size_t)64*512*4;
  p.qT  =(ushort_t*)(w+off);       off += (size_t)64*512*2;
  p.oT  =(ushort_t*)(w+off);       off += (size_t)64*512*2;
  p.gT  =(ushort_t*)(w+off);       off += (size_t)64*2048*2;
  p.wq  =(ushort_t*)(w+off);       off += (size_t)8*512*1536*2;
  p.wp  =(ushort_t*)(w+off);       off += (size_t)8*512*512*2;
  p.wf  =(ushort_t*)(w+off);       off += (size_t)8*512*2048*2;
  p.wm  =(ushort_t*)(w+off);       off += (size_t)8*2048*512*2;
  p.Kc  =(ushort_t*)(w+off);       off += (size_t)L_*64*8*T_*64*2;
  p.Vc  =(ushort_t*)(w+off);       off += (size_t)L_*64*8*T_*64*2;

  fprintf(stderr, "[gptloop] ws_size=%zu need=%zu\n", ws_size, off);
  if (ws_size < off) return;

  hipMemsetAsync(d_ws, 0, 16384, stream);
  hipLaunchKernelGGL(wconv, dim3(1024), dim3(256), 0, stream, p.qkv_w,  p.wq, 8*512*1536);
  hipLaunchKernelGGL(wconv, dim3(1024), dim3(256), 0, stream, p.proj_w, p.wp, 8*512*512);
  hipLaunchKernelGGL(wconv, dim3(1024), dim3(256), 0, stream, p.fc_w,   p.wf, 8*512*2048);
  hipLaunchKernelGGL(wconv, dim3(1024), dim3(256), 0, stream, p.mproj_w,p.wm, 8*2048*512);
  hipLaunchKernelGGL(gptloop, dim3(NWG), dim3(NT), 0, stream, p);
}